// Round 1
// baseline (507.120 us; speedup 1.0000x reference)
//
#include <hip/hip_runtime.h>
#include <hip/hip_fp16.h>

// PureGCN forward. R7: SpMM restructured as XCD-aligned feature slicing.
// Evidence: spmm FETCH_SIZE 201.5MB ~= 8 XCDs x 25.6MB H -- each XCD's random
// src gathers thrash its private 4MB L2 (working set ~22MB). Fix: H stored
// slice-major (8 slices x 16 features x N, 3.2MB each); spmm grid puts
// slice = blockIdx&7 so slice s runs on XCD s (round-robin dispatch) -> gather
// working set L2-resident. Edge records compressed to 4B (src 17b | w 15b
// fixed-point), CSR rows padded to x4 for aligned dwordx4 rec loads, fixed
// bucket stride kills k_build's global scan. Layer-1 LN moved to a separate
// small pass (sliced blocks can't see full rows). k_bin grid 256->782.

constexpr int N_NODES = 100000;
constexpr int N_EDGES = 1600000;
constexpr int HID     = 128;
constexpr int NBKT    = (N_NODES + 511) / 512;   // 196 buckets of 512 nodes
constexpr int BCAP    = 9216;                    // raw bucket capacity (mean 8192)
constexpr int BSTRIDE = 11264;                   // padded bucket stride (<= 9216 + 3*512, x4)
constexpr float LN_EPS = 1e-5f;

typedef __attribute__((ext_vector_type(8))) short short8;   // 8 bf16
typedef __attribute__((ext_vector_type(4))) float floatx4;  // MFMA acc
typedef __attribute__((ext_vector_type(4))) unsigned u32x4;
typedef __attribute__((ext_vector_type(2))) float f32x2;

__device__ inline unsigned pack_bf16x2(float a, float b) {
    unsigned ua = __float_as_uint(a), ub = __float_as_uint(b);
    ua += 0x7fff + ((ua >> 16) & 1);          // RNE
    ub += 0x7fff + ((ub >> 16) & 1);
    return (ua >> 16) | (ub & 0xffff0000u);
}
__device__ inline float bflo(unsigned u) { return __uint_as_float(u << 16); }
__device__ inline float bfhi(unsigned u) { return __uint_as_float(u & 0xffff0000u); }

// ---------------- phase 1: bucket edges by dst>>9 (LDS multisplit) ----------------
// record: (w15 << 17) | src, w15 = round(w * 32768) clamped to 32767 (w in [0,1))
__global__ __launch_bounds__(256) void k_bin(const int* __restrict__ ei,
                                             const float* __restrict__ ef,
                                             int* __restrict__ gcur,
                                             int* __restrict__ gbufDst,
                                             unsigned* __restrict__ gbufRec) {
    __shared__ int cnt[NBKT];
    __shared__ int incl[256];
    __shared__ int gbase[NBKT];
    __shared__ int sdst[2048];
    __shared__ unsigned ssw[2048];
    const int t = threadIdx.x;

    for (int e0 = blockIdx.x * 2048; e0 < N_EDGES; e0 += gridDim.x * 2048) {
        for (int i = t; i < NBKT; i += 256) cnt[i] = 0;
        __syncthreads();

        const int nE = min(2048, N_EDGES - e0);
        int ed[8], ep[8]; unsigned er[8];
        const int base = e0 + t * 8;
        if (base + 8 <= N_EDGES) {
            int4 s0 = *(const int4*)&ei[base];
            int4 s1 = *(const int4*)&ei[base + 4];
            int4 d0 = *(const int4*)&ei[N_EDGES + base];
            int4 d1 = *(const int4*)&ei[N_EDGES + base + 4];
            float4 w0 = *(const float4*)&ef[base];
            float4 w1 = *(const float4*)&ef[base + 4];
            int es[8]; float ew[8];
            es[0]=s0.x; es[1]=s0.y; es[2]=s0.z; es[3]=s0.w;
            es[4]=s1.x; es[5]=s1.y; es[6]=s1.z; es[7]=s1.w;
            ed[0]=d0.x; ed[1]=d0.y; ed[2]=d0.z; ed[3]=d0.w;
            ed[4]=d1.x; ed[5]=d1.y; ed[6]=d1.z; ed[7]=d1.w;
            ew[0]=w0.x; ew[1]=w0.y; ew[2]=w0.z; ew[3]=w0.w;
            ew[4]=w1.x; ew[5]=w1.y; ew[6]=w1.z; ew[7]=w1.w;
#pragma unroll
            for (int k = 0; k < 8; ++k) {
                unsigned q = __float2uint_rn(ew[k] * 32768.0f);
                if (q > 32767u) q = 32767u;
                er[k] = (q << 17) | (unsigned)es[k];
                ep[k] = atomicAdd(&cnt[ed[k] >> 9], 1);
            }
        } else {
#pragma unroll
            for (int k = 0; k < 8; ++k) {
                int idx = base + k;
                if (idx < N_EDGES) {
                    int s = ei[idx]; ed[k] = ei[N_EDGES + idx];
                    unsigned q = __float2uint_rn(ef[idx] * 32768.0f);
                    if (q > 32767u) q = 32767u;
                    er[k] = (q << 17) | (unsigned)s;
                    ep[k] = atomicAdd(&cnt[ed[k] >> 9], 1);
                } else ed[k] = -1;
            }
        }
        __syncthreads();

        int v = (t < NBKT) ? cnt[t] : 0;
        incl[t] = v;
        for (int o = 1; o < 256; o <<= 1) {
            __syncthreads();
            int u = (t >= o) ? incl[t - o] : 0;
            __syncthreads();
            incl[t] += u;
        }
        __syncthreads();
        if (t < NBKT) gbase[t] = atomicAdd(&gcur[t], v);
        __syncthreads();

#pragma unroll
        for (int k = 0; k < 8; ++k) {
            if (ed[k] < 0) continue;
            int b = ed[k] >> 9;
            int idx = incl[b] - cnt[b] + ep[k];
            sdst[idx] = ed[k];
            ssw[idx]  = er[k];
        }
        __syncthreads();

        for (int j = t; j < nE; j += 256) {
            int d = sdst[j];
            int b = d >> 9;
            int pos = gbase[b] + (j - (incl[b] - cnt[b]));
            if (pos < BCAP) {
                gbufDst[(size_t)b * BCAP + pos] = d;
                gbufRec[(size_t)b * BCAP + pos] = ssw[j];
            }
        }
        __syncthreads();
    }
}

// ---------------- phase 2: per-bucket counting sort -> padded CSR ----------------
// Fixed bucket stride (no inter-bucket scan). Rows padded to x4 with zero
// records (w=0, src=0). rowinfo[node] = (beg << 10) | deg, beg multiple of 4.
__global__ __launch_bounds__(512) void k_build(const int* __restrict__ gcur,
                                               const int* __restrict__ gbufDst,
                                               const unsigned* __restrict__ gbufRec,
                                               unsigned* __restrict__ rowinfo,
                                               unsigned* __restrict__ rec) {
    __shared__ int cnt[512];
    __shared__ int cur[512];
    __shared__ unsigned sorted[BSTRIDE];
    const int t     = threadIdx.x;
    const int b     = blockIdx.x;
    const int nbase = b * 512;
    const int nb    = min(gcur[b], BCAP);
    const unsigned cb = (unsigned)b * (unsigned)BSTRIDE;

    cnt[t] = 0;
    for (int i = t; i < BSTRIDE; i += 512) sorted[i] = 0;
    __syncthreads();

    const int*      bd = gbufDst + (size_t)b * BCAP;
    const unsigned* bs = gbufRec + (size_t)b * BCAP;

    for (int i = t; i < nb; i += 512) atomicAdd(&cnt[bd[i] - nbase], 1);
    __syncthreads();

    const int deg = cnt[t];
    int v = (deg + 3) & ~3;               // pad each row to multiple of 4
    cur[t] = v;
    for (int o = 1; o < 512; o <<= 1) {
        __syncthreads();
        int u = (t >= o) ? cur[t - o] : 0;
        __syncthreads();
        cur[t] += u;
    }
    __syncthreads();
    const int padTotal = cur[511];
    const int excl = cur[t] - v;
    __syncthreads();
    cur[t] = excl;
    if (nbase + t < N_NODES)
        rowinfo[nbase + t] = ((cb + (unsigned)excl) << 10) | (unsigned)deg;
    __syncthreads();

    for (int i = t; i < nb; i += 512) {
        int d = bd[i];
        int pos = atomicAdd(&cur[d - nbase], 1);
        sorted[pos] = bs[i];
    }
    __syncthreads();
    for (int i = t; i < padTotal; i += 512) rec[(size_t)cb + i] = sorted[i];
}

// ---------------- MFMA GEMM + LN0 + ReLU ----------------
// writes orib (bf16 pre-LN, row-major) and hact (bf16 post-LN/ReLU, SLICE-MAJOR:
// hact[slice][node][8 u32], slice stride = N*8 u32 = 3.2MB -> L2-fits one XCD)
__global__ __launch_bounds__(256) void k_gemm_mfma(const float* __restrict__ x,
                                                   const float* __restrict__ W,
                                                   const float* __restrict__ bias,
                                                   const float* __restrict__ lns,
                                                   const float* __restrict__ lnb,
                                                   unsigned* __restrict__ orib,
                                                   unsigned* __restrict__ hact) {
    __shared__ __align__(16) char smem[128 * 136 * 2 + 64 * 136 * 2];
    ushort (*Ws)[136] = (ushort(*)[136])smem;
    ushort (*Xs)[136] = (ushort(*)[136])(smem + 128 * 136 * 2);
    float  (*Hs)[132] = (float(*)[132])smem;

    const int t    = threadIdx.x;
    const int row0 = blockIdx.x * 64;

    {   // stage W fp32 -> bf16
        const float4* Wf = (const float4*)W;
#pragma unroll
        for (int i = 0; i < 8; ++i) {
            int g = t + 256 * i;
            float4 p = Wf[g * 2], q = Wf[g * 2 + 1];
            uint4 vv = make_uint4(pack_bf16x2(p.x, p.y), pack_bf16x2(p.z, p.w),
                                  pack_bf16x2(q.x, q.y), pack_bf16x2(q.z, q.w));
            int r = g >> 4;
            int c = (g & 15) * 8;
            *(uint4*)&Ws[r][c] = vv;
        }
    }
    {   // stage x tile -> bf16
        const float4* xg = (const float4*)x;
        const int base = blockIdx.x * 2048;
#pragma unroll
        for (int i = 0; i < 8; ++i) {
            int f = t + 256 * i;
            int g = base + f;
            float4 vv = make_float4(0.f, 0.f, 0.f, 0.f);
            if (g < N_NODES * 32) vv = xg[g];
            int r = f >> 5;
            int c = (f & 31) * 4;
            uint2 p = make_uint2(pack_bf16x2(vv.x, vv.y), pack_bf16x2(vv.z, vv.w));
            *(uint2*)&Xs[r][c] = p;
        }
    }
    __syncthreads();

    const int wv   = t >> 6;
    const int l    = t & 63;
    const int mrow = l & 15;
    const int kq   = l >> 4;

    floatx4 acc[8];
#pragma unroll
    for (int i = 0; i < 8; ++i) acc[i] = (floatx4){0.f, 0.f, 0.f, 0.f};

#pragma unroll
    for (int ks = 0; ks < 4; ++ks) {
        short8 a = *(const short8*)&Xs[wv * 16 + mrow][ks * 32 + kq * 8];
#pragma unroll
        for (int tc = 0; tc < 8; ++tc) {
            short8 bb = *(const short8*)&Ws[tc * 16 + mrow][ks * 32 + kq * 8];
            acc[tc] = __builtin_amdgcn_mfma_f32_16x16x32_bf16(a, bb, acc[tc], 0, 0, 0);
        }
    }
    __syncthreads();

#pragma unroll
    for (int tc = 0; tc < 8; ++tc)
#pragma unroll
        for (int r = 0; r < 4; ++r)
            Hs[wv * 16 + kq * 4 + r][tc * 16 + mrow] = acc[tc][r];
    __syncthreads();

    const float2 b2  = ((const float2*)bias)[l];
    const float2 sc2 = ((const float2*)lns)[l];
    const float2 bb2 = ((const float2*)lnb)[l];
    for (int rr = 0; rr < 16; ++rr) {
        const int lrow = wv * 16 + rr;
        const int grow = row0 + lrow;
        if (grow >= N_NODES) break;
        float2 vv = *(const float2*)&Hs[lrow][l * 2];
        vv.x += b2.x; vv.y += b2.y;
        orib[(size_t)grow * 64 + l] = pack_bf16x2(vv.x, vv.y);
        float s  = vv.x + vv.y;
        float s2 = vv.x * vv.x + vv.y * vv.y;
#pragma unroll
        for (int m = 1; m < 64; m <<= 1) {
            s  += __shfl_xor(s, m);
            s2 += __shfl_xor(s2, m);
        }
        const float mu   = s * (1.0f / 128.0f);
        const float var  = s2 * (1.0f / 128.0f) - mu * mu;
        const float rstd = rsqrtf(var + LN_EPS);
        float y0 = fmaxf((vv.x - mu) * rstd * sc2.x + bb2.x, 0.0f);
        float y1 = fmaxf((vv.y - mu) * rstd * sc2.y + bb2.y, 0.0f);
        // slice-major store: slice = l>>3 (16 features), col = l&7
        hact[(size_t)(l >> 3) * (size_t)(N_NODES * 8) + (size_t)grow * 8 + (l & 7)] =
            pack_bf16x2(y0, y1);
    }
}

// ---------------- sliced SpMM ----------------
// grid = 3125*8 blocks; slice = blockIdx&7 -> lands on XCD (blockIdx%8), so each
// XCD only gathers from its 3.2MB slice region (L2-resident). Wave = 8 nodes x
// 8 u32 cols; per round each node-group loads one aligned dwordx4 of records
// (nontemporal) and issues 4 independent 32B gathers.
__device__ inline void spmm_slice(const unsigned* __restrict__ rowinfo,
                                  const unsigned* __restrict__ rec,
                                  const unsigned* __restrict__ Hb,
                                  float& ax, float& ay,
                                  int& node, int& slice, int& col) {
    const int lane = threadIdx.x & 63;
    slice = blockIdx.x & 7;
    const int nb = blockIdx.x >> 3;
    const int wv = threadIdx.x >> 6;
    const int sub = lane >> 3;
    col = lane & 7;
    node = nb * 32 + wv * 8 + sub;                    // 3125*32 = 100000 exact

    const unsigned info = rowinfo[node];
    const int myBeg = (int)(info >> 10);              // multiple of 4
    const int myDeg = (int)(info & 1023u);
    const unsigned* Hs = Hb + (size_t)slice * (size_t)(N_NODES * 8) + col;
    const u32x4* recv = (const u32x4*)(rec + myBeg);  // 16B-aligned

    ax = 0.f; ay = 0.f;
    for (int off = 0; __any(off < myDeg); off += 4) {
        u32x4 R = {0u, 0u, 0u, 0u};
        if (off < myDeg) R = __builtin_nontemporal_load(recv + (off >> 2));
        unsigned v0 = Hs[(size_t)(R[0] & 0x1FFFFu) * 8u];
        unsigned v1 = Hs[(size_t)(R[1] & 0x1FFFFu) * 8u];
        unsigned v2 = Hs[(size_t)(R[2] & 0x1FFFFu) * 8u];
        unsigned v3 = Hs[(size_t)(R[3] & 0x1FFFFu) * 8u];
        float w0 = (float)(R[0] >> 17);
        float w1 = (float)(R[1] >> 17);
        float w2 = (float)(R[2] >> 17);
        float w3 = (float)(R[3] >> 17);
        ax = fmaf(w0, bflo(v0), ax); ay = fmaf(w0, bfhi(v0), ay);
        ax = fmaf(w1, bflo(v1), ax); ay = fmaf(w1, bfhi(v1), ay);
        ax = fmaf(w2, bflo(v2), ax); ay = fmaf(w2, bfhi(v2), ay);
        ax = fmaf(w3, bflo(v3), ax); ay = fmaf(w3, bfhi(v3), ay);
    }
    ax *= 3.0517578125e-05f;    // 1/32768 (defer fixed-point scale out of loop)
    ay *= 3.0517578125e-05f;
}

// layer-1 spmm: aggregate -> f16x2-packed row-major agg (consumed by k_ln)
__global__ __launch_bounds__(256) void k_spmm_agg(const unsigned* __restrict__ rowinfo,
                                                  const unsigned* __restrict__ rec,
                                                  const unsigned* __restrict__ Hb,
                                                  unsigned* __restrict__ agg) {
    float ax, ay; int node, slice, col;
    spmm_slice(rowinfo, rec, Hb, ax, ay, node, slice, col);
    unsigned u = (unsigned)__half_as_ushort(__float2half(ax)) |
                 ((unsigned)__half_as_ushort(__float2half(ay)) << 16);
    __builtin_nontemporal_store(u, agg + (size_t)node * 64 + slice * 8 + col);
}

// layer-2 spmm: aggregate -> f32 output (row-major [N,128])
__global__ __launch_bounds__(256) void k_spmm_f32(const unsigned* __restrict__ rowinfo,
                                                  const unsigned* __restrict__ rec,
                                                  const unsigned* __restrict__ Hb,
                                                  float* __restrict__ out) {
    float ax, ay; int node, slice, col;
    spmm_slice(rowinfo, rec, Hb, ax, ay, node, slice, col);
    f32x2 o2 = {ax, ay};
    __builtin_nontemporal_store(o2, (f32x2*)out + (size_t)node * 64 + slice * 8 + col);
}

// ---------------- residual + LN1 + ReLU (full-row pass) ----------------
// reads f16 agg + bf16 orib (row-major), writes hact2 slice-major for layer-2 spmm
__global__ __launch_bounds__(256) void k_ln(const unsigned* __restrict__ agg,
                                            const unsigned* __restrict__ orib,
                                            const float* __restrict__ lns,
                                            const float* __restrict__ lnb,
                                            unsigned* __restrict__ hact2) {
    const int wid  = (blockIdx.x * 256 + threadIdx.x) >> 6;   // node
    const int lane = threadIdx.x & 63;
    unsigned a = agg[(size_t)wid * 64 + lane];
    unsigned o = orib[(size_t)wid * 64 + lane];
    float vx = __half2float(__ushort_as_half((unsigned short)(a & 0xffffu))) + bflo(o);
    float vy = __half2float(__ushort_as_half((unsigned short)(a >> 16)))     + bfhi(o);
    float s  = vx + vy;
    float s2 = vx * vx + vy * vy;
#pragma unroll
    for (int m = 1; m < 64; m <<= 1) {
        s  += __shfl_xor(s, m);
        s2 += __shfl_xor(s2, m);
    }
    const float mu   = s * (1.0f / 128.0f);
    const float var  = s2 * (1.0f / 128.0f) - mu * mu;
    const float rstd = rsqrtf(var + LN_EPS);
    const float2 sc = ((const float2*)lns)[lane];
    const float2 bb = ((const float2*)lnb)[lane];
    float y0 = fmaxf((vx - mu) * rstd * sc.x + bb.x, 0.0f);
    float y1 = fmaxf((vy - mu) * rstd * sc.y + bb.y, 0.0f);
    hact2[(size_t)(lane >> 3) * (size_t)(N_NODES * 8) + (size_t)wid * 8 + (lane & 7)] =
        pack_bf16x2(y0, y1);
}

extern "C" void kernel_launch(void* const* d_in, const int* in_sizes, int n_in,
                              void* d_out, int out_size, void* d_ws, size_t ws_size,
                              hipStream_t stream) {
    const float* x   = (const float*)d_in[0];
    const int*   ei  = (const int*)d_in[1];
    const float* ef  = (const float*)d_in[2];
    const float* W   = (const float*)d_in[3];
    const float* b   = (const float*)d_in[4];
    const float* lns = (const float*)d_in[5];
    const float* lnb = (const float*)d_in[6];
    float* out = (float*)d_out;

    // d_out scratch: bf16 orib in lower 25.6MB, f16 agg in upper 25.6MB
    // (both consumed by k_ln before k_spmm_f32 overwrites all of d_out)
    unsigned* orib = (unsigned*)d_out;
    unsigned* agg  = (unsigned*)d_out + (size_t)N_NODES * 64;

    unsigned* rec     = (unsigned*)d_ws;                        // NBKT*BSTRIDE
    unsigned* hact    = rec + (size_t)NBKT * BSTRIDE;           // N*64 u32 (slice-major)
    unsigned* hact2   = hact + (size_t)N_NODES * 64;            // N*64 u32 (slice-major)
    unsigned* gbufRec = hact2 + (size_t)N_NODES * 64;           // NBKT*BCAP
    int*      gcur    = (int*)(gbufRec + (size_t)NBKT * BCAP);  // NBKT
    unsigned* rowinfo = (unsigned*)(gcur + NBKT);               // N
    int*      gbufDst = (int*)(rowinfo + N_NODES);              // NBKT*BCAP

    hipMemsetAsync(gcur, 0, NBKT * sizeof(int), stream);
    k_bin<<<782, 256, 0, stream>>>(ei, ef, gcur, gbufDst, gbufRec);
    k_build<<<NBKT, 512, 0, stream>>>(gcur, gbufDst, gbufRec, rowinfo, rec);

    k_gemm_mfma<<<(N_NODES + 63) / 64, 256, 0, stream>>>(x, W, b, lns, lnb, orib, hact);

    k_spmm_agg<<<25000, 256, 0, stream>>>(rowinfo, rec, hact, agg);
    k_ln<<<25000, 256, 0, stream>>>(agg, orib, lns + HID, lnb + HID, hact2);
    k_spmm_f32<<<25000, 256, 0, stream>>>(rowinfo, rec, hact2, out);
}

// Round 2
// 384.361 us; speedup vs baseline: 1.3194x; 1.3194x over previous
//
#include <hip/hip_runtime.h>
#include <hip/hip_fp16.h>

// PureGCN forward. R8: sliced SpMM, pipelined. R7 proved the XCD slicing cuts
// fetch 201->85MB but its per-round {rec load -> 4 gathers} serial chain made it
// latency-bound (0.8 TB/s, 147us). R8 keeps the slicing and restores R6's
// concurrency: one wave owns 8 consecutive nodes of one slice (their CSR rows
// are contiguous, padded to x8); node m+1's record loads issue before node m's
// gathers (3 rec + 3 gathers ~6 vmem in flight/wave); rec loads cached (not nt)
// so 32B requests line-fill L2 once. deg>24 tail (2.2% of nodes) via uniform
// residual loop. Fabric floor ~15MB/XCD -> ~33us/spmm at 450GB/s/XCD.

constexpr int N_NODES = 100000;
constexpr int N_EDGES = 1600000;
constexpr int HID     = 128;
constexpr int NBKT    = (N_NODES + 511) / 512;   // 196 buckets of 512 nodes
constexpr int BCAP    = 9216;                    // raw bucket capacity (mean 8192)
constexpr int BSTRIDE = 12800;                   // BCAP + 512*7 (x8 row padding), x8
constexpr float LN_EPS = 1e-5f;

typedef __attribute__((ext_vector_type(8))) short short8;   // 8 bf16
typedef __attribute__((ext_vector_type(4))) float floatx4;  // MFMA acc
typedef __attribute__((ext_vector_type(2))) float f32x2;

__device__ inline unsigned pack_bf16x2(float a, float b) {
    unsigned ua = __float_as_uint(a), ub = __float_as_uint(b);
    ua += 0x7fff + ((ua >> 16) & 1);          // RNE
    ub += 0x7fff + ((ub >> 16) & 1);
    return (ua >> 16) | (ub & 0xffff0000u);
}
__device__ inline float bflo(unsigned u) { return __uint_as_float(u << 16); }
__device__ inline float bfhi(unsigned u) { return __uint_as_float(u & 0xffff0000u); }

// ---------------- phase 1: bucket edges by dst>>9 (LDS multisplit) ----------------
// record: (w15 << 17) | src, w15 = round(w * 32768) clamped to 32767 (w in [0,1))
__global__ __launch_bounds__(256) void k_bin(const int* __restrict__ ei,
                                             const float* __restrict__ ef,
                                             int* __restrict__ gcur,
                                             int* __restrict__ gbufDst,
                                             unsigned* __restrict__ gbufRec) {
    __shared__ int cnt[NBKT];
    __shared__ int incl[256];
    __shared__ int gbase[NBKT];
    __shared__ int sdst[2048];
    __shared__ unsigned ssw[2048];
    const int t = threadIdx.x;

    for (int e0 = blockIdx.x * 2048; e0 < N_EDGES; e0 += gridDim.x * 2048) {
        for (int i = t; i < NBKT; i += 256) cnt[i] = 0;
        __syncthreads();

        const int nE = min(2048, N_EDGES - e0);
        int ed[8], ep[8]; unsigned er[8];
        const int base = e0 + t * 8;
        if (base + 8 <= N_EDGES) {
            int4 s0 = *(const int4*)&ei[base];
            int4 s1 = *(const int4*)&ei[base + 4];
            int4 d0 = *(const int4*)&ei[N_EDGES + base];
            int4 d1 = *(const int4*)&ei[N_EDGES + base + 4];
            float4 w0 = *(const float4*)&ef[base];
            float4 w1 = *(const float4*)&ef[base + 4];
            int es[8]; float ew[8];
            es[0]=s0.x; es[1]=s0.y; es[2]=s0.z; es[3]=s0.w;
            es[4]=s1.x; es[5]=s1.y; es[6]=s1.z; es[7]=s1.w;
            ed[0]=d0.x; ed[1]=d0.y; ed[2]=d0.z; ed[3]=d0.w;
            ed[4]=d1.x; ed[5]=d1.y; ed[6]=d1.z; ed[7]=d1.w;
            ew[0]=w0.x; ew[1]=w0.y; ew[2]=w0.z; ew[3]=w0.w;
            ew[4]=w1.x; ew[5]=w1.y; ew[6]=w1.z; ew[7]=w1.w;
#pragma unroll
            for (int k = 0; k < 8; ++k) {
                unsigned q = __float2uint_rn(ew[k] * 32768.0f);
                if (q > 32767u) q = 32767u;
                er[k] = (q << 17) | (unsigned)es[k];
                ep[k] = atomicAdd(&cnt[ed[k] >> 9], 1);
            }
        } else {
#pragma unroll
            for (int k = 0; k < 8; ++k) {
                int idx = base + k;
                if (idx < N_EDGES) {
                    int s = ei[idx]; ed[k] = ei[N_EDGES + idx];
                    unsigned q = __float2uint_rn(ef[idx] * 32768.0f);
                    if (q > 32767u) q = 32767u;
                    er[k] = (q << 17) | (unsigned)s;
                    ep[k] = atomicAdd(&cnt[ed[k] >> 9], 1);
                } else ed[k] = -1;
            }
        }
        __syncthreads();

        int v = (t < NBKT) ? cnt[t] : 0;
        incl[t] = v;
        for (int o = 1; o < 256; o <<= 1) {
            __syncthreads();
            int u = (t >= o) ? incl[t - o] : 0;
            __syncthreads();
            incl[t] += u;
        }
        __syncthreads();
        if (t < NBKT) gbase[t] = atomicAdd(&gcur[t], v);
        __syncthreads();

#pragma unroll
        for (int k = 0; k < 8; ++k) {
            if (ed[k] < 0) continue;
            int b = ed[k] >> 9;
            int idx = incl[b] - cnt[b] + ep[k];
            sdst[idx] = ed[k];
            ssw[idx]  = er[k];
        }
        __syncthreads();

        for (int j = t; j < nE; j += 256) {
            int d = sdst[j];
            int b = d >> 9;
            int pos = gbase[b] + (j - (incl[b] - cnt[b]));
            if (pos < BCAP) {
                gbufDst[(size_t)b * BCAP + pos] = d;
                gbufRec[(size_t)b * BCAP + pos] = ssw[j];
            }
        }
        __syncthreads();
    }
}

// ---------------- phase 2: per-bucket counting sort -> padded CSR ----------------
// Rows padded to x8 with zero records (w=0, src=0). rowinfo[node] = (beg<<10)|deg.
__global__ __launch_bounds__(512) void k_build(const int* __restrict__ gcur,
                                               const int* __restrict__ gbufDst,
                                               const unsigned* __restrict__ gbufRec,
                                               unsigned* __restrict__ rowinfo,
                                               unsigned* __restrict__ rec) {
    __shared__ int cnt[512];
    __shared__ int cur[512];
    __shared__ unsigned sorted[BSTRIDE];
    const int t     = threadIdx.x;
    const int b     = blockIdx.x;
    const int nbase = b * 512;
    const int nb    = min(gcur[b], BCAP);
    const unsigned cb = (unsigned)b * (unsigned)BSTRIDE;

    cnt[t] = 0;
    for (int i = t; i < BSTRIDE; i += 512) sorted[i] = 0;
    __syncthreads();

    const int*      bd = gbufDst + (size_t)b * BCAP;
    const unsigned* bs = gbufRec + (size_t)b * BCAP;

    for (int i = t; i < nb; i += 512) atomicAdd(&cnt[bd[i] - nbase], 1);
    __syncthreads();

    const int deg = cnt[t];
    int v = (deg + 7) & ~7;               // pad each row to multiple of 8
    cur[t] = v;
    for (int o = 1; o < 512; o <<= 1) {
        __syncthreads();
        int u = (t >= o) ? cur[t - o] : 0;
        __syncthreads();
        cur[t] += u;
    }
    __syncthreads();
    const int padTotal = cur[511];
    const int excl = cur[t] - v;
    __syncthreads();
    cur[t] = excl;
    if (nbase + t < N_NODES)
        rowinfo[nbase + t] = ((cb + (unsigned)excl) << 10) | (unsigned)deg;
    __syncthreads();

    for (int i = t; i < nb; i += 512) {
        int d = bd[i];
        int pos = atomicAdd(&cur[d - nbase], 1);
        sorted[pos] = bs[i];
    }
    __syncthreads();
    for (int i = t; i < padTotal; i += 512) rec[(size_t)cb + i] = sorted[i];
}

// ---------------- MFMA GEMM + LN0 + ReLU ----------------
// writes orib (bf16 pre-LN, row-major) and hact (bf16 post-LN/ReLU, SLICE-MAJOR:
// hact[slice][node][8 u32], slice stride = N*8 u32 = 3.2MB -> L2-fits one XCD)
__global__ __launch_bounds__(256) void k_gemm_mfma(const float* __restrict__ x,
                                                   const float* __restrict__ W,
                                                   const float* __restrict__ bias,
                                                   const float* __restrict__ lns,
                                                   const float* __restrict__ lnb,
                                                   unsigned* __restrict__ orib,
                                                   unsigned* __restrict__ hact) {
    __shared__ __align__(16) char smem[128 * 136 * 2 + 64 * 136 * 2];
    ushort (*Ws)[136] = (ushort(*)[136])smem;
    ushort (*Xs)[136] = (ushort(*)[136])(smem + 128 * 136 * 2);
    float  (*Hs)[132] = (float(*)[132])smem;

    const int t    = threadIdx.x;
    const int row0 = blockIdx.x * 64;

    {   // stage W fp32 -> bf16
        const float4* Wf = (const float4*)W;
#pragma unroll
        for (int i = 0; i < 8; ++i) {
            int g = t + 256 * i;
            float4 p = Wf[g * 2], q = Wf[g * 2 + 1];
            uint4 vv = make_uint4(pack_bf16x2(p.x, p.y), pack_bf16x2(p.z, p.w),
                                  pack_bf16x2(q.x, q.y), pack_bf16x2(q.z, q.w));
            int r = g >> 4;
            int c = (g & 15) * 8;
            *(uint4*)&Ws[r][c] = vv;
        }
    }
    {   // stage x tile -> bf16
        const float4* xg = (const float4*)x;
        const int base = blockIdx.x * 2048;
#pragma unroll
        for (int i = 0; i < 8; ++i) {
            int f = t + 256 * i;
            int g = base + f;
            float4 vv = make_float4(0.f, 0.f, 0.f, 0.f);
            if (g < N_NODES * 32) vv = xg[g];
            int r = f >> 5;
            int c = (f & 31) * 4;
            uint2 p = make_uint2(pack_bf16x2(vv.x, vv.y), pack_bf16x2(vv.z, vv.w));
            *(uint2*)&Xs[r][c] = p;
        }
    }
    __syncthreads();

    const int wv   = t >> 6;
    const int l    = t & 63;
    const int mrow = l & 15;
    const int kq   = l >> 4;

    floatx4 acc[8];
#pragma unroll
    for (int i = 0; i < 8; ++i) acc[i] = (floatx4){0.f, 0.f, 0.f, 0.f};

#pragma unroll
    for (int ks = 0; ks < 4; ++ks) {
        short8 a = *(const short8*)&Xs[wv * 16 + mrow][ks * 32 + kq * 8];
#pragma unroll
        for (int tc = 0; tc < 8; ++tc) {
            short8 bb = *(const short8*)&Ws[tc * 16 + mrow][ks * 32 + kq * 8];
            acc[tc] = __builtin_amdgcn_mfma_f32_16x16x32_bf16(a, bb, acc[tc], 0, 0, 0);
        }
    }
    __syncthreads();

#pragma unroll
    for (int tc = 0; tc < 8; ++tc)
#pragma unroll
        for (int r = 0; r < 4; ++r)
            Hs[wv * 16 + kq * 4 + r][tc * 16 + mrow] = acc[tc][r];
    __syncthreads();

    const float2 b2  = ((const float2*)bias)[l];
    const float2 sc2 = ((const float2*)lns)[l];
    const float2 bb2 = ((const float2*)lnb)[l];
    for (int rr = 0; rr < 16; ++rr) {
        const int lrow = wv * 16 + rr;
        const int grow = row0 + lrow;
        if (grow >= N_NODES) break;
        float2 vv = *(const float2*)&Hs[lrow][l * 2];
        vv.x += b2.x; vv.y += b2.y;
        orib[(size_t)grow * 64 + l] = pack_bf16x2(vv.x, vv.y);
        float s  = vv.x + vv.y;
        float s2 = vv.x * vv.x + vv.y * vv.y;
#pragma unroll
        for (int m = 1; m < 64; m <<= 1) {
            s  += __shfl_xor(s, m);
            s2 += __shfl_xor(s2, m);
        }
        const float mu   = s * (1.0f / 128.0f);
        const float var  = s2 * (1.0f / 128.0f) - mu * mu;
        const float rstd = rsqrtf(var + LN_EPS);
        float y0 = fmaxf((vv.x - mu) * rstd * sc2.x + bb2.x, 0.0f);
        float y1 = fmaxf((vv.y - mu) * rstd * sc2.y + bb2.y, 0.0f);
        // slice-major store: slice = l>>3 (16 features), col = l&7
        hact[(size_t)(l >> 3) * (size_t)(N_NODES * 8) + (size_t)grow * 8 + (l & 7)] =
            pack_bf16x2(y0, y1);
    }
}

// ---------------- sliced SpMM, 8 nodes/wave, cross-node pipelined ----------------
// slice = blockIdx&7 -> XCD-pinned (3.2MB H slice L2-resident). Wave = 8 subs x
// 8 cols; per node, 3 predicated 32B rec loads cover deg<=24 (97.8%); node m+1
// recs issue before node m's gathers -> ~6 vmem in flight/wave. deg>24 residual
// loop is wave-uniform. Reduce over subs via 3x shfl_xor, 8-lane store.
template <int MODE>   // 0: f16x2 agg store, 1: f32 out store
__global__ __launch_bounds__(256) void k_spmm(const unsigned* __restrict__ rowinfo,
                                              const unsigned* __restrict__ rec,
                                              const unsigned* __restrict__ Hb,
                                              unsigned* __restrict__ agg,
                                              float* __restrict__ out) {
    const int slice = blockIdx.x & 7;
    const int nb    = blockIdx.x >> 3;            // 0..3124
    const int wv    = threadIdx.x >> 6;
    const int lane  = threadIdx.x & 63;
    const int sub   = lane >> 3;
    const int col   = lane & 7;
    const int node0 = nb * 32 + wv * 8;           // 3125*32 = 100000 exact

    const unsigned* __restrict__ Hs = Hb + (size_t)slice * (size_t)(N_NODES * 8) + col;

    // rowinfo for this wave's 8 nodes (one 32B request, lanes replicate x8)
    const unsigned vinfo = rowinfo[node0 + (lane & 7)];

    int beg, pd;
    unsigned cr0, cr1, cr2;
    {
        unsigned info = __shfl(vinfo, 0);
        beg = (int)(info >> 10);
        int deg = (int)(info & 1023u);
        pd = (deg + 7) & ~7;
        cr0 = (sub < pd)      ? rec[beg + sub]      : 0u;
        cr1 = (8  + sub < pd) ? rec[beg + 8 + sub]  : 0u;
        cr2 = (16 + sub < pd) ? rec[beg + 16 + sub] : 0u;
    }

#pragma unroll
    for (int m = 0; m < 8; ++m) {
        const int cbeg = beg, cpd = pd;
        unsigned nr0 = 0u, nr1 = 0u, nr2 = 0u;
        if (m < 7) {   // prefetch node m+1's records before this node's gathers
            unsigned info = __shfl(vinfo, m + 1);
            beg = (int)(info >> 10);
            int deg = (int)(info & 1023u);
            pd = (deg + 7) & ~7;
            nr0 = (sub < pd)      ? rec[beg + sub]      : 0u;
            nr1 = (8  + sub < pd) ? rec[beg + 8 + sub]  : 0u;
            nr2 = (16 + sub < pd) ? rec[beg + 16 + sub] : 0u;
        }

        unsigned v0 = Hs[(size_t)(cr0 & 0x1FFFFu) * 8u];
        unsigned v1 = Hs[(size_t)(cr1 & 0x1FFFFu) * 8u];
        unsigned v2 = Hs[(size_t)(cr2 & 0x1FFFFu) * 8u];
        float w0 = (float)(cr0 >> 17), w1 = (float)(cr1 >> 17), w2 = (float)(cr2 >> 17);
        float ax = w0 * bflo(v0), ay = w0 * bfhi(v0);
        ax = fmaf(w1, bflo(v1), ax); ay = fmaf(w1, bfhi(v1), ay);
        ax = fmaf(w2, bflo(v2), ax); ay = fmaf(w2, bfhi(v2), ay);

        for (int e = 24; e < cpd; e += 8) {       // deg>24 tail (2.2% of nodes)
            unsigned r = (e + sub < cpd) ? rec[cbeg + e + sub] : 0u;
            unsigned v = Hs[(size_t)(r & 0x1FFFFu) * 8u];
            float w = (float)(r >> 17);
            ax = fmaf(w, bflo(v), ax); ay = fmaf(w, bfhi(v), ay);
        }

        ax += __shfl_xor(ax, 8);  ay += __shfl_xor(ay, 8);
        ax += __shfl_xor(ax, 16); ay += __shfl_xor(ay, 16);
        ax += __shfl_xor(ax, 32); ay += __shfl_xor(ay, 32);
        ax *= 3.0517578125e-05f;                   // 1/32768 fixed-point scale
        ay *= 3.0517578125e-05f;

        if (sub == 0) {
            const int node = node0 + m;
            if (MODE == 0) {
                unsigned u = (unsigned)__half_as_ushort(__float2half(ax)) |
                             ((unsigned)__half_as_ushort(__float2half(ay)) << 16);
                __builtin_nontemporal_store(u, agg + (size_t)node * 64 + slice * 8 + col);
            } else {
                f32x2 o2 = {ax, ay};
                __builtin_nontemporal_store(o2, (f32x2*)out + (size_t)node * 64 + slice * 8 + col);
            }
        }
        cr0 = nr0; cr1 = nr1; cr2 = nr2;
    }
}

// ---------------- residual + LN1 + ReLU (full-row pass) ----------------
// reads f16 agg + bf16 orib (row-major), writes hact2 slice-major for layer-2 spmm
__global__ __launch_bounds__(256) void k_ln(const unsigned* __restrict__ agg,
                                            const unsigned* __restrict__ orib,
                                            const float* __restrict__ lns,
                                            const float* __restrict__ lnb,
                                            unsigned* __restrict__ hact2) {
    const int wid  = (blockIdx.x * 256 + threadIdx.x) >> 6;   // node
    const int lane = threadIdx.x & 63;
    unsigned a = agg[(size_t)wid * 64 + lane];
    unsigned o = orib[(size_t)wid * 64 + lane];
    float vx = __half2float(__ushort_as_half((unsigned short)(a & 0xffffu))) + bflo(o);
    float vy = __half2float(__ushort_as_half((unsigned short)(a >> 16)))     + bfhi(o);
    float s  = vx + vy;
    float s2 = vx * vx + vy * vy;
#pragma unroll
    for (int m = 1; m < 64; m <<= 1) {
        s  += __shfl_xor(s, m);
        s2 += __shfl_xor(s2, m);
    }
    const float mu   = s * (1.0f / 128.0f);
    const float var  = s2 * (1.0f / 128.0f) - mu * mu;
    const float rstd = rsqrtf(var + LN_EPS);
    const float2 sc = ((const float2*)lns)[lane];
    const float2 bb = ((const float2*)lnb)[lane];
    float y0 = fmaxf((vx - mu) * rstd * sc.x + bb.x, 0.0f);
    float y1 = fmaxf((vy - mu) * rstd * sc.y + bb.y, 0.0f);
    hact2[(size_t)(lane >> 3) * (size_t)(N_NODES * 8) + (size_t)wid * 8 + (lane & 7)] =
        pack_bf16x2(y0, y1);
}

extern "C" void kernel_launch(void* const* d_in, const int* in_sizes, int n_in,
                              void* d_out, int out_size, void* d_ws, size_t ws_size,
                              hipStream_t stream) {
    const float* x   = (const float*)d_in[0];
    const int*   ei  = (const int*)d_in[1];
    const float* ef  = (const float*)d_in[2];
    const float* W   = (const float*)d_in[3];
    const float* b   = (const float*)d_in[4];
    const float* lns = (const float*)d_in[5];
    const float* lnb = (const float*)d_in[6];
    float* out = (float*)d_out;

    // d_out scratch: bf16 orib in lower 25.6MB, f16 agg in upper 25.6MB
    // (both consumed by k_ln before k_spmm<1> overwrites all of d_out)
    unsigned* orib = (unsigned*)d_out;
    unsigned* agg  = (unsigned*)d_out + (size_t)N_NODES * 64;

    unsigned* rec     = (unsigned*)d_ws;                        // NBKT*BSTRIDE (10.0MB)
    unsigned* hact    = rec + (size_t)NBKT * BSTRIDE;           // N*64 u32 (slice-major)
    unsigned* hact2   = hact + (size_t)N_NODES * 64;            // N*64 u32 (slice-major)
    unsigned* gbufRec = hact2 + (size_t)N_NODES * 64;           // NBKT*BCAP
    int*      gcur    = (int*)(gbufRec + (size_t)NBKT * BCAP);  // NBKT
    unsigned* rowinfo = (unsigned*)(gcur + NBKT);               // N
    int*      gbufDst = (int*)(rowinfo + N_NODES);              // NBKT*BCAP

    hipMemsetAsync(gcur, 0, NBKT * sizeof(int), stream);
    k_bin<<<782, 256, 0, stream>>>(ei, ef, gcur, gbufDst, gbufRec);
    k_build<<<NBKT, 512, 0, stream>>>(gcur, gbufDst, gbufRec, rowinfo, rec);

    k_gemm_mfma<<<(N_NODES + 63) / 64, 256, 0, stream>>>(x, W, b, lns, lnb, orib, hact);

    k_spmm<0><<<25000, 256, 0, stream>>>(rowinfo, rec, hact, agg, nullptr);
    k_ln<<<25000, 256, 0, stream>>>(agg, orib, lns + HID, lnb + HID, hact2);
    k_spmm<1><<<25000, 256, 0, stream>>>(rowinfo, rec, hact2, nullptr, out);
}